// Round 14
// baseline (95.989 us; speedup 1.0000x reference)
//
#include <hip/hip_runtime.h>

#define ALPHA 0.25f
#define EPS   1e-8f
// COST_CLASS=2, COST_BBOX=5, COST_GIOU=2

// Problem constants (from setup_inputs): bs=16, Q=900, C=80, g_size=3
constexpr int BS = 16;
constexpr int QN = 900;
constexpr int CN = 80;
constexpr int GS = 3;
constexpr int QG2 = 2;                       // query-groups per block
constexpr int ROWS2 = QG2 * GS;              // 6 pred rows
constexpr int CC_STRIDE = 8;                 // cc row: 2 groups x 4-float quads
constexpr int NT_THREADS = 320;              // 5 waves; 1600/320 = 5 exact iters

// ---------------------------------------------------------------------------
// v11: v10 (champion, kernel ~29.5us) + 2 query-groups per block sharing one
//  target stream.
//  Ledger (kernel us, fill-normalized): v5(1200blk)=39.6, v6(4800blk)=31,
//  v8(960blk)=35.8, v9(2-body ILP)=30.5, v10(depth-2 prefetch)=29.5.
//  In v10 each thread pays {tgt load + 7 per-t scalars + prologue share} for
//  only 3 pair-bodies. QG2=2 amortizes all three 2x: one tr/lab load feeds 6
//  bodies; grid 150x16=2400 blocks still >= 1536 resident slots -> TLP (the
//  proven lever) unchanged. Body math byte-identical to v5/v6/v10.
//  Depth-2 prefetch and the generic-T fallback carried over from v10.
// ---------------------------------------------------------------------------
template<int NITER>   // >0: exact compile-time trip count; 0: generic runtime
__global__ __launch_bounds__(NT_THREADS, 4) void fused_cost_kernel(
    const float* __restrict__ pred_logits,  // [BS*QN, CN]
    const float* __restrict__ pred_boxes,   // [BS*QN, 4] cxcywh
    const int*   __restrict__ tgt_labels,   // [T]
    const float* __restrict__ tgt_boxes,    // [T, 4] cxcywh
    float*       __restrict__ out,          // [BS, QN/GS, T]
    int T)
{
    __shared__ __align__(16) float s_cc_t[CN * CC_STRIDE];  // [80][8] = 2560 B

    const int tid = threadIdx.x;
    const int qg0 = blockIdx.x * QG2;       // first of 2 query-groups
    const int b   = blockIdx.y;
    const int n0  = b * QN + qg0 * GS;      // first of 6 pred rows

    // ---- focal class-cost rows, transposed into LDS ----
    // 480 logits over 320 threads (2 strided steps; threads >=160 do 1).
    const float* lg0 = pred_logits + (size_t)n0 * CN;
    for (int idx = tid; idx < ROWS2 * CN; idx += NT_THREADS) {
        const float x = lg0[idx];
        const int r  = idx / CN;            // 0..5
        const int c  = idx - r * CN;
        const int g  = r / GS;              // group 0/1
        const int rr = r - g * GS;          // row in group 0..2
        float p = __fdividef(1.0f, 1.0f + __expf(-x));  // sigmoid
        float omp = 1.0f - p;
        float pos = ALPHA * omp * omp * (-__logf(p + EPS));
        float neg = (1.0f - ALPHA) * p * p * (-__logf(omp + EPS));
        s_cc_t[c * CC_STRIDE + g * 4 + rr] = pos - neg;
    }

    // ---- 6 pred rows -> wave-uniform registers (v6-exact per row) ----
    float Px0[ROWS2], Py0[ROWS2], Px1[ROWS2], Py1[ROWS2];
    float Pcx2[ROWS2], Pcy2[ROWS2], Pw[ROWS2], Ph[ROWS2], Pa[ROWS2];
    #pragma unroll
    for (int r = 0; r < ROWS2; ++r) {
        const float4 pb = ((const float4*)pred_boxes)[n0 + r];
        Pw[r]   = pb.z;               Ph[r]   = pb.w;
        Pa[r]   = pb.z * pb.w;
        Pcx2[r] = pb.x + pb.x;        Pcy2[r] = pb.y + pb.y;
        Px0[r]  = pb.x - 0.5f * pb.z; Py0[r]  = pb.y - 0.5f * pb.w;
        Px1[r]  = pb.x + 0.5f * pb.z; Py1[r]  = pb.y + 0.5f * pb.w;
    }
    __syncthreads();

    float* const o0 = out + (size_t)(b * (QN / GS) + qg0) * T;

    // body: one target against BOTH groups (6 pairs), 2 stores.
    // per-pair math byte-identical to v5/v6/v10.
    auto body = [&](int t, const float4 tr, int lab) {
        // shared per-t scalars (once for 6 pairs)
        const float tx0 = tr.x - 0.5f * tr.z, ty0 = tr.y - 0.5f * tr.w;
        const float tx1 = tr.x + 0.5f * tr.z, ty1 = tr.y + 0.5f * tr.w;
        const float ta  = tr.z * tr.w;
        const float tcx2 = tr.x + tr.x, tcy2 = tr.y + tr.y;

        #pragma unroll
        for (int g = 0; g < QG2; ++g) {
            const float4 ccq =
                *((const float4*)&s_cc_t[lab * CC_STRIDE + g * 4]);
            const float ccv[GS] = { ccq.x, ccq.y, ccq.z };

            float m = -3.402823466e+38f;
            #pragma unroll
            for (int i = 0; i < GS; ++i) {
                const int r = g * GS + i;

                const float ix0 = fmaxf(Px0[r], tx0);
                const float iy0 = fmaxf(Py0[r], ty0);
                const float ix1 = fminf(Px1[r], tx1);
                const float iy1 = fminf(Py1[r], ty1);
                const float iw  = fmaxf(ix1 - ix0, 0.0f);
                const float ih  = fmaxf(iy1 - iy0, 0.0f);
                const float inter = iw * ih;

                const float ex0 = fminf(Px0[r], tx0);
                const float ey0 = fminf(Py0[r], ty0);
                const float ex1 = fmaxf(Px1[r], tx1);
                const float ey1 = fmaxf(Py1[r], ty1);
                const float earea = (ex1 - ex0) * (ey1 - ey0);

                const float uni = (Pa[r] + ta) - inter;

                const float h1 = fabsf(Pcx2[r] - tcx2) + fabsf(Pcy2[r] - tcy2);
                const float h2 = fabsf(Pw[r] - tr.z) + fabsf(Ph[r] - tr.w);
                const float l1 = fmaf(0.5f, h1, h2);

                const float num = fmaf(inter, earea, uni * uni);
                const float den = uni * earea;
                const float q   = num * __builtin_amdgcn_rcpf(den);

                const float cost = fmaf(5.0f, l1,
                                    fmaf(2.0f, ccv[i], fmaf(-2.0f, q, 2.0f)));
                m = fmaxf(m, cost);
            }
            __builtin_nontemporal_store(m, o0 + (size_t)g * T + t);
        }
    };

    if constexpr (NITER > 0) {
        // depth-2 rolled pipeline (v10-verified): A = cur, B = +1, fetch +2
        int t = tid;
        float4 trA = ((const float4*)tgt_boxes)[t];
        int    laA = tgt_labels[t];
        float4 trB = ((const float4*)tgt_boxes)[t + NT_THREADS];
        int    laB = tgt_labels[t + NT_THREADS];

        for (int it = 0; it < NITER; ++it) {
            const int tf = t + 2 * NT_THREADS;
            const int tfc = (tf < T) ? tf : tid;        // clamped safe addr
            const float4 trC = ((const float4*)tgt_boxes)[tfc];
            const int    laC = tgt_labels[tfc];

            body(t, trA, laA);

            t += NT_THREADS;
            trA = trB; laA = laB;
            trB = trC; laB = laC;
        }
    } else {
        // generic rolled loop with depth-1 prefetch (v6-verified pattern)
        const int nIter = (T + NT_THREADS - 1) / NT_THREADS;
        int t = tid;
        int tl = (t < T) ? t : (T - 1);
        float4 tr  = ((const float4*)tgt_boxes)[tl];
        int    lab = tgt_labels[tl];
        for (int it = 0; it < nIter; ++it) {
            const int tn = t + NT_THREADS;
            const int tc = (tn < T) ? tn : tl;
            const float4 trn  = ((const float4*)tgt_boxes)[tc];
            const int    labn = tgt_labels[tc];
            if (t < T) body(t, tr, lab);
            t = tn; tl = tc; tr = trn; lab = labn;
        }
    }
}

extern "C" void kernel_launch(void* const* d_in, const int* in_sizes, int n_in,
                              void* d_out, int out_size, void* d_ws, size_t ws_size,
                              hipStream_t stream) {
    const float* pred_logits = (const float*)d_in[0];   // [16,900,80]
    const float* pred_boxes  = (const float*)d_in[1];   // [16,900,4]
    const int*   tgt_labels  = (const int*)d_in[2];     // [T]
    const float* tgt_boxes   = (const float*)d_in[3];   // [T,4]
    // d_in[4] = g_size (=3, hard-coded as GS)

    const int T = in_sizes[2];
    float* out = (float*)d_out;

    dim3 grid((QN / GS) / QG2, BS);                      // 150 x 16 = 2400
    if (T == NT_THREADS * 5) {
        fused_cost_kernel<5><<<grid, NT_THREADS, 0, stream>>>(
            pred_logits, pred_boxes, tgt_labels, tgt_boxes, out, T);
    } else {
        fused_cost_kernel<0><<<grid, NT_THREADS, 0, stream>>>(
            pred_logits, pred_boxes, tgt_labels, tgt_boxes, out, T);
    }
}

// Round 15
// 90.027 us; speedup vs baseline: 1.0662x; 1.0662x over previous
//
#include <hip/hip_runtime.h>

#define ALPHA 0.25f
#define EPS   1e-8f
// COST_CLASS=2, COST_BBOX=5, COST_GIOU=2

// Problem constants (from setup_inputs): bs=16, Q=900, C=80, g_size=3
constexpr int BS = 16;
constexpr int QN = 900;
constexpr int CN = 80;
constexpr int GS = 3;
constexpr int ROWS = GS;                     // 3 pred rows = 1 query-group per block
constexpr int CC_STRIDE = 4;                 // class-cost row padded to 4 floats (16B)
constexpr int NT_THREADS = 320;              // 5 waves; 1600/320 = 5 exact iters

// ---------------------------------------------------------------------------
// v10 (RESTORED champion, kernel ~29.5us fill-normalized, e2e 89.6us).
//  Final ledger (kernel us): v3/v5(1200blk)=39.6, v6(4800blk)=31,
//  v8(960blk wave-private)=35.8 REV, v9(2-body ILP)=30.5 neutral,
//  v10(depth-2 prefetch)=29.5 CHAMPION, v11(QG2 amortize, 2400blk)=36 REV.
//  Lessons: resident TLP with maximal independent fine blocks is the
//  controlling variable; every tile-widening/amortization move regressed;
//  full unroll (v7) broke graph-replay determinism.
//  Structure: 1 query-group (3 pred rows) per 320-thread block, grid 300x16;
//  per-wave-uniform pred rows in registers; 80x4 padded class-cost LDS table
//  (1 ds_read_b128 per t); depth-2 rolled target prefetch; nontemporal
//  stores; scalar xyxy min/max pair math with rcpf divide (v5-verified).
// ---------------------------------------------------------------------------
template<int NITER>   // >0: exact compile-time trip count; 0: generic runtime
__global__ __launch_bounds__(NT_THREADS, 4) void fused_cost_kernel(
    const float* __restrict__ pred_logits,  // [BS*QN, CN]
    const float* __restrict__ pred_boxes,   // [BS*QN, 4] cxcywh
    const int*   __restrict__ tgt_labels,   // [T]
    const float* __restrict__ tgt_boxes,    // [T, 4] cxcywh
    float*       __restrict__ out,          // [BS, QN/GS, T]
    int T)
{
    __shared__ __align__(16) float s_cc_t[CN * CC_STRIDE];  // [80][4] = 1280 B

    const int tid = threadIdx.x;
    const int qg0 = blockIdx.x;             // one query-group per block
    const int b   = blockIdx.y;
    const int n0  = b * QN + qg0 * GS;      // first of 3 pred rows

    // ---- focal class-cost rows, transposed into LDS (240 threads x 1) ----
    const float* lg0 = pred_logits + (size_t)n0 * CN;
    if (tid < ROWS * CN) {
        const float x = lg0[tid];
        const int r = tid / CN;
        const int c = tid - r * CN;
        float p = __fdividef(1.0f, 1.0f + __expf(-x));  // sigmoid
        float omp = 1.0f - p;
        float pos = ALPHA * omp * omp * (-__logf(p + EPS));
        float neg = (1.0f - ALPHA) * p * p * (-__logf(omp + EPS));
        s_cc_t[c * CC_STRIDE + r] = pos - neg;
    }

    // ---- pred rows -> wave-uniform registers (v6 exact) ----
    float Px0[ROWS], Py0[ROWS], Px1[ROWS], Py1[ROWS];
    float Pcx2[ROWS], Pcy2[ROWS], Pw[ROWS], Ph[ROWS], Pa[ROWS];
    #pragma unroll
    for (int r = 0; r < ROWS; ++r) {
        const float4 pb = ((const float4*)pred_boxes)[n0 + r];
        Pw[r]   = pb.z;               Ph[r]   = pb.w;
        Pa[r]   = pb.z * pb.w;
        Pcx2[r] = pb.x + pb.x;        Pcy2[r] = pb.y + pb.y;
        Px0[r]  = pb.x - 0.5f * pb.z; Py0[r]  = pb.y - 0.5f * pb.w;
        Px1[r]  = pb.x + 0.5f * pb.z; Py1[r]  = pb.y + 0.5f * pb.w;
    }
    __syncthreads();

    float* const o0 = out + (size_t)(b * (QN / GS) + qg0) * T;

    // body: per-t cost + group-max + store (byte-identical math to v5/v6)
    auto body = [&](int t, const float4 tr, int lab) {
        const float4 ccq = *((const float4*)&s_cc_t[lab * CC_STRIDE]);
        const float ccv[ROWS] = { ccq.x, ccq.y, ccq.z };

        const float tx0 = tr.x - 0.5f * tr.z, ty0 = tr.y - 0.5f * tr.w;
        const float tx1 = tr.x + 0.5f * tr.z, ty1 = tr.y + 0.5f * tr.w;
        const float ta  = tr.z * tr.w;
        const float tcx2 = tr.x + tr.x, tcy2 = tr.y + tr.y;

        float m = -3.402823466e+38f;
        #pragma unroll
        for (int i = 0; i < ROWS; ++i) {
            const float ix0 = fmaxf(Px0[i], tx0);
            const float iy0 = fmaxf(Py0[i], ty0);
            const float ix1 = fminf(Px1[i], tx1);
            const float iy1 = fminf(Py1[i], ty1);
            const float iw  = fmaxf(ix1 - ix0, 0.0f);
            const float ih  = fmaxf(iy1 - iy0, 0.0f);
            const float inter = iw * ih;

            const float ex0 = fminf(Px0[i], tx0);
            const float ey0 = fminf(Py0[i], ty0);
            const float ex1 = fmaxf(Px1[i], tx1);
            const float ey1 = fmaxf(Py1[i], ty1);
            const float earea = (ex1 - ex0) * (ey1 - ey0);

            const float uni = (Pa[i] + ta) - inter;

            const float h1 = fabsf(Pcx2[i] - tcx2) + fabsf(Pcy2[i] - tcy2);
            const float h2 = fabsf(Pw[i] - tr.z) + fabsf(Ph[i] - tr.w);
            const float l1 = fmaf(0.5f, h1, h2);

            const float num = fmaf(inter, earea, uni * uni);
            const float den = uni * earea;
            const float q   = num * __builtin_amdgcn_rcpf(den);

            const float cost = fmaf(5.0f, l1,
                                fmaf(2.0f, ccv[i], fmaf(-2.0f, q, 2.0f)));
            m = fmaxf(m, cost);
        }
        __builtin_nontemporal_store(m, o0 + t);
    };

    if constexpr (NITER > 0) {
        // depth-2 rolled pipeline: A = current, B = +1, prefetch C = +2
        int t = tid;
        float4 trA = ((const float4*)tgt_boxes)[t];
        int    laA = tgt_labels[t];
        float4 trB = ((const float4*)tgt_boxes)[t + NT_THREADS];   // <= 639: ok
        int    laB = tgt_labels[t + NT_THREADS];

        for (int it = 0; it < NITER; ++it) {
            const int tf = t + 2 * NT_THREADS;          // prefetch index
            const int tfc = (tf < T) ? tf : tid;        // clamped safe addr
            const float4 trC = ((const float4*)tgt_boxes)[tfc];
            const int    laC = tgt_labels[tfc];

            body(t, trA, laA);

            t += NT_THREADS;
            trA = trB; laA = laB;
            trB = trC; laB = laC;
        }
    } else {
        // generic rolled loop with depth-1 prefetch (v6-verified pattern)
        const int nIter = (T + NT_THREADS - 1) / NT_THREADS;
        int t = tid;
        int tl = (t < T) ? t : (T - 1);
        float4 tr  = ((const float4*)tgt_boxes)[tl];
        int    lab = tgt_labels[tl];
        for (int it = 0; it < nIter; ++it) {
            const int tn = t + NT_THREADS;
            const int tc = (tn < T) ? tn : tl;
            const float4 trn  = ((const float4*)tgt_boxes)[tc];
            const int    labn = tgt_labels[tc];
            if (t < T) body(t, tr, lab);
            t = tn; tl = tc; tr = trn; lab = labn;
        }
    }
}

extern "C" void kernel_launch(void* const* d_in, const int* in_sizes, int n_in,
                              void* d_out, int out_size, void* d_ws, size_t ws_size,
                              hipStream_t stream) {
    const float* pred_logits = (const float*)d_in[0];   // [16,900,80]
    const float* pred_boxes  = (const float*)d_in[1];   // [16,900,4]
    const int*   tgt_labels  = (const int*)d_in[2];     // [T]
    const float* tgt_boxes   = (const float*)d_in[3];   // [T,4]
    // d_in[4] = g_size (=3, hard-coded as GS)

    const int T = in_sizes[2];
    float* out = (float*)d_out;

    dim3 grid(QN / GS, BS);                              // 300 x 16 = 4800
    if (T == NT_THREADS * 5) {
        fused_cost_kernel<5><<<grid, NT_THREADS, 0, stream>>>(
            pred_logits, pred_boxes, tgt_labels, tgt_boxes, out, T);
    } else {
        fused_cost_kernel<0><<<grid, NT_THREADS, 0, stream>>>(
            pred_logits, pred_boxes, tgt_labels, tgt_boxes, out, T);
    }
}